// Round 4
// baseline (178.094 us; speedup 1.0000x reference)
//
#include <hip/hip_runtime.h>

// Varifold loss, round 16: MFMA shape 32x32x16 -> 16x16x16 (same K=16 dot,
// same 32-f16 record format, 4-f16 lane slices). Accumulators shrink from
// f32x16 (16 regs) to f32x4 (4 regs): iteration = 8 skewed blocks of 256
// pairs (4 i-subtiles x 2 j-col-halves) with ping-pong Tp/Dp accumulators,
// peak acc liveness 16 regs vs 64. Total footprint ~70 unified regs ->
// __launch_bounds__(256,6) is feasible (cap 85) -> 6 waves/SIMD vs 4,
// +50% latency cover for the exp2-dominated epilogue. exp/pk work per
// pair unchanged; MFMA count x4 but matrix pipe ~15% busy (free).
// Panels 256 rows, SPLITS=26, signs/weights identical to round-12.
//
// t_ij = cq_i + cq_j + TG*<C_i,C_j>;  d_ij = <m_i,m_j>;  term = exp2(t)*d^2.
// A-op K=16: [TGh(3),TGl(3),TGh(3),TGl(3),cqh,cql,1,1]
// B-op K=16: [Ch(3),Ch(3),Cl(3),Cl(3),1,1,cqh,cql]
// d:  A=[mh,ml,mh,ml,0^4], B=[mh,mh,ml,ml,0^4]   (exact hi/lo split)

#define NVERT 5023
#define NFACE 9976
#define BATCH 4
#define HALFP 9984             // per-mesh faces padded: 39 panels x 256
#define NTP   (2 * HALFP)      // 19968 faces per batch
#define NTOT  (BATCH * NTP)    // 79872
#define NCH   624              // j-chunks of 32 per batch
#define NPAN  78               // i-panels of 256
#define SPLITS 26

constexpr float GAMMA = 1.0f / (0.03f * 0.03f);
constexpr float LOG2E = 1.4426950408889634f;
constexpr float EPSV  = 1e-12f;

typedef _Float16 half8_t  __attribute__((ext_vector_type(8)));
typedef _Float16 half4_t  __attribute__((ext_vector_type(4)));
typedef float    f32x4    __attribute__((ext_vector_type(4)));
typedef float    f32x2    __attribute__((ext_vector_type(2)));

__global__ __launch_bounds__(256)
void face_quant_kernel(const float* __restrict__ pred,
                       const float* __restrict__ targ,
                       const int*   __restrict__ faces,
                       _Float16*    __restrict__ fd,
                       float*       __restrict__ out) {
    int idx = blockIdx.x * 256 + threadIdx.x;
    if (idx == 0) out[0] = 0.0f;
    if (idx >= NTOT) return;

    int b     = idx / NTP;
    int s     = idx - b * NTP;
    int which = (s >= HALFP) ? 1 : 0;
    int f     = s - which * HALFP;

    _Float16* arec = fd + (size_t)idx * 32;
    _Float16* brec = fd + (size_t)NTOT * 32 + (size_t)idx * 32;

    if (f >= NFACE) {
        half8_t z = {};
        *(half8_t*)(arec + 0) = z; *(half8_t*)(arec + 8)  = z;
        *(half8_t*)(arec + 16) = z; *(half8_t*)(arec + 24) = z;
        *(half8_t*)(brec + 0) = z; *(half8_t*)(brec + 8)  = z;
        *(half8_t*)(brec + 16) = z; *(half8_t*)(brec + 24) = z;
        return;
    }

    const float* V = (which ? targ : pred) + (size_t)b * NVERT * 3;
    int i0 = faces[f * 3 + 0];
    int i1 = faces[f * 3 + 1];
    int i2 = faces[f * 3 + 2];

    float v0x = V[i0*3+0], v0y = V[i0*3+1], v0z = V[i0*3+2];
    float v1x = V[i1*3+0], v1y = V[i1*3+1], v1z = V[i1*3+2];
    float v2x = V[i2*3+0], v2y = V[i2*3+1], v2z = V[i2*3+2];

    const float third = 1.0f / 3.0f;
    float cx = (v0x + v1x + v2x) * third;
    float cy = (v0y + v1y + v2y) * third;
    float cz = (v0z + v1z + v2z) * third;

    float e1x = v1x - v0x, e1y = v1y - v0y, e1z = v1z - v0z;
    float e2x = v2x - v0x, e2y = v2y - v0y, e2z = v2z - v0z;

    float nx = 0.5f * (e1y * e2z - e1z * e2y);
    float ny = 0.5f * (e1z * e2x - e1x * e2z);
    float nz = 0.5f * (e1x * e2y - e1y * e2x);

    float L   = sqrtf(nx*nx + ny*ny + nz*nz);
    float inv = 1.0f / fmaxf(L, EPSV);
    float sc  = inv * sqrtf(L);            // m = Nn*sqrt(L)
    float mx = nx * sc, my = ny * sc, mz = nz * sc;

    const float TG = 2.0f * GAMMA * LOG2E;
    float tgx = TG * cx, tgy = TG * cy, tgz = TG * cz;
    float cq  = -GAMMA * LOG2E * (cx*cx + cy*cy + cz*cz);

    _Float16 TGxh = (_Float16)tgx; _Float16 TGxl = (_Float16)(tgx - (float)TGxh);
    _Float16 TGyh = (_Float16)tgy; _Float16 TGyl = (_Float16)(tgy - (float)TGyh);
    _Float16 TGzh = (_Float16)tgz; _Float16 TGzl = (_Float16)(tgz - (float)TGzh);
    _Float16 Cxh  = (_Float16)cx;  _Float16 Cxl  = (_Float16)(cx  - (float)Cxh);
    _Float16 Cyh  = (_Float16)cy;  _Float16 Cyl  = (_Float16)(cy  - (float)Cyh);
    _Float16 Czh  = (_Float16)cz;  _Float16 Czl  = (_Float16)(cz  - (float)Czh);
    _Float16 cqh  = (_Float16)cq;  _Float16 cql  = (_Float16)(cq  - (float)cqh);
    _Float16 mxh  = (_Float16)mx;  _Float16 mxl  = (_Float16)(mx  - (float)mxh);
    _Float16 myh  = (_Float16)my;  _Float16 myl  = (_Float16)(my  - (float)myh);
    _Float16 mzh  = (_Float16)mz;  _Float16 mzl  = (_Float16)(mz  - (float)mzh);
    _Float16 one  = (_Float16)1.0f;
    _Float16 zz   = (_Float16)0.0f;

    half8_t ta0 = {TGxh, TGyh, TGzh, TGxl, TGyl, TGzl, TGxh, TGyh};
    half8_t ta1 = {TGzh, TGxl, TGyl, TGzl, cqh,  cql,  one,  one };
    half8_t da0 = {mxh,  myh,  mzh,  mxl,  myl,  mzl,  mxh,  myh };
    half8_t da1 = {mzh,  mxl,  myl,  mzl,  zz,   zz,   zz,   zz  };
    half8_t tb0 = {Cxh,  Cyh,  Czh,  Cxh,  Cyh,  Czh,  Cxl,  Cyl };
    half8_t tb1 = {Czl,  Cxl,  Cyl,  Czl,  one,  one,  cqh,  cql };
    half8_t db0 = {mxh,  myh,  mzh,  mxh,  myh,  mzh,  mxl,  myl };
    half8_t db1 = {mzl,  mxl,  myl,  mzl,  zz,   zz,   zz,   zz  };

    *(half8_t*)(arec + 0)  = ta0;  *(half8_t*)(arec + 8)  = ta1;
    *(half8_t*)(arec + 16) = da0;  *(half8_t*)(arec + 24) = da1;
    *(half8_t*)(brec + 0)  = tb0;  *(half8_t*)(brec + 8)  = tb1;
    *(half8_t*)(brec + 16) = db0;  *(half8_t*)(brec + 24) = db1;
}

__device__ __forceinline__ half4_t ld4(const _Float16* p) {
    return *(const half4_t*)p;
}

__global__ __launch_bounds__(256, 6)
void pair_sum_kernel(const _Float16* __restrict__ fd,
                     float*          __restrict__ out) {
    const int b       = blockIdx.z;
    const int pairIdx = blockIdx.x / SPLITS;     // 0..38
    const int s       = blockIdx.x % SPLITS;

    const _Float16* Arec = fd;
    const _Float16* Brec = fd + (size_t)NTOT * 32;

    const int lane = threadIdx.x & 63;
    const int w    = threadIdx.x >> 6;
    const int col  = lane & 15;          // 16x16: col/row within tile
    const int kof  = (lane >> 4) * 4;    // k-slice: 0/4/8/12

    const size_t bface = (size_t)b * NTP;
    const size_t JSTEP = (size_t)SPLITS * 32 * 32;

    float acc = 0.0f;

    #pragma unroll 1
    for (int h = 0; h < 2; ++h) {
        const int   P  = h ? (NPAN - 1 - pairIdx) : pairIdx;
        const int   c0 = 8 * P;
        const float si = (P < NPAN / 2) ? 1.0f : -1.0f;
        const int   iters = (NCH - c0 - s + SPLITS - 1) / SPLITS;
        if (iters <= 0) continue;

        // A operands: this wave owns 64 rows = 4 subtiles of 16
        const _Float16* abase =
            Arec + (bface + (size_t)(P * 256 + w * 64 + col)) * 32 + kof;
        half4_t aT[4], aD[4];
        #pragma unroll
        for (int st = 0; st < 4; ++st) {
            aT[st] = ld4(abase + (size_t)st * 16 * 32);
            aD[st] = ld4(abase + (size_t)st * 16 * 32 + 16);
        }

        // B: chunk (c0+s), cols 0-15 and 16-31
        const _Float16* pB =
            Brec + (bface + (size_t)((c0 + s) * 32 + col)) * 32 + kof;
        half4_t bT0 = ld4(pB),       bD0 = ld4(pB + 16);
        half4_t bT1 = ld4(pB + 512), bD1 = ld4(pB + 528);

        const f32x4 z4 = {};

        #pragma unroll 1
        for (int k = 0; k < iters; ++k) {
            // depth-1 branchless prefetch (clamped); full-iteration distance
            const _Float16* pN = (k + 1 < iters) ? (pB + JSTEP) : pB;
            half4_t nT0 = ld4(pN),       nD0 = ld4(pN + 16);
            half4_t nT1 = ld4(pN + 512), nD1 = ld4(pN + 528);
            pB = pN;

            f32x2 aa0 = {0.f, 0.f}, aa1 = {0.f, 0.f};

            // 8 skewed blocks of 256 pairs; ping-pong Tp/Dp keeps peak
            // accumulator liveness at 2 blocks (16 regs).
            f32x4 Tp = __builtin_amdgcn_mfma_f32_16x16x16f16(aT[0], bT0, z4, 0, 0, 0);
            f32x4 Dp = __builtin_amdgcn_mfma_f32_16x16x16f16(aD[0], bD0, z4, 0, 0, 0);

#define EPI4(T_, D_)                                                      \
            {                                                             \
                f32x2 e0_ = {__builtin_amdgcn_exp2f((T_)[0]),             \
                             __builtin_amdgcn_exp2f((T_)[1])};            \
                f32x2 e1_ = {__builtin_amdgcn_exp2f((T_)[2]),             \
                             __builtin_amdgcn_exp2f((T_)[3])};            \
                f32x2 d0_ = {(D_)[0], (D_)[1]};                           \
                f32x2 d1_ = {(D_)[2], (D_)[3]};                           \
                d0_ = d0_ * d0_;                                          \
                d1_ = d1_ * d1_;                                          \
                aa0 = e0_ * d0_ + aa0;                                    \
                aa1 = e1_ * d1_ + aa1;                                    \
            }

#define STEP(AT_, BT_, AD_, BD_)                                          \
            {                                                             \
                f32x4 Tc = __builtin_amdgcn_mfma_f32_16x16x16f16(         \
                    (AT_), (BT_), z4, 0, 0, 0);                           \
                f32x4 Dc = __builtin_amdgcn_mfma_f32_16x16x16f16(         \
                    (AD_), (BD_), z4, 0, 0, 0);                           \
                EPI4(Tp, Dp);                                             \
                Tp = Tc; Dp = Dc;                                         \
            }

            STEP(aT[1], bT0, aD[1], bD0)
            STEP(aT[2], bT0, aD[2], bD0)
            STEP(aT[3], bT0, aD[3], bD0)
            STEP(aT[0], bT1, aD[0], bD1)
            STEP(aT[1], bT1, aD[1], bD1)
            STEP(aT[2], bT1, aD[2], bD1)
            STEP(aT[3], bT1, aD[3], bD1)
            EPI4(Tp, Dp);
#undef STEP
#undef EPI4

            const int   jc  = c0 + s + SPLITS * k;
            const float sj  = (jc < NCH / 2) ? si : -si;
            const float wgt = (k == 0 && s < 8) ? 1.0f : 2.0f;
            f32x2 A2 = aa0 + aa1;
            acc = fmaf(sj * wgt, A2.x + A2.y, acc);

            bT0 = nT0; bD0 = nD0; bT1 = nT1; bD1 = nD1;
        }
    }

    acc *= (1.0f / BATCH);

    #pragma unroll
    for (int off = 32; off > 0; off >>= 1)
        acc += __shfl_down(acc, off, 64);

    __shared__ float wsum[4];
    const int lane2 = threadIdx.x & 63;
    const int w2    = threadIdx.x >> 6;
    if (lane2 == 0) wsum[w2] = acc;
    __syncthreads();
    if (threadIdx.x == 0)
        atomicAdd(out, wsum[0] + wsum[1] + wsum[2] + wsum[3]);
}

extern "C" void kernel_launch(void* const* d_in, const int* in_sizes, int n_in,
                              void* d_out, int out_size, void* d_ws, size_t ws_size,
                              hipStream_t stream) {
    const float* pred  = (const float*)d_in[0];
    const float* targ  = (const float*)d_in[1];
    const int*   faces = (const int*)d_in[2];
    float*       out   = (float*)d_out;
    _Float16*    fd    = (_Float16*)d_ws;   // 2 arrays x 79872 faces x 64 B = 10.2 MB

    face_quant_kernel<<<(NTOT + 255) / 256, 256, 0, stream>>>(
        pred, targ, faces, fd, out);

    dim3 grid((NPAN / 2) * SPLITS, 1, BATCH);   // 1014 x 1 x 4 = 4056 blocks
    pair_sum_kernel<<<grid, 256, 0, stream>>>(fd, out);
}

// Round 5
// 160.652 us; speedup vs baseline: 1.1086x; 1.1086x over previous
//
#include <hip/hip_runtime.h>

// Varifold loss, round 17: EXACT round-12 structure (2 i-tiles/wave,
// 256-row panels, SPLITS=26, 32x32x16 f16 MFMA, 4 accumulators) with ONE
// zero-register-cost change: per-wave circular k-loop stagger. Wave w
// starts its j-chunk loop at k0 = w*iters/4 and wraps, decorrelating the
// 4 waves' MFMA-latency stall windows so they cover each other (round-12
// showed VALUBusy 73% == per-wave duty cycle -> waves were phase-locked).
// Signs/weights derive from the actual chunk index k, so numerics are
// identical up to summation order (already nondeterministic via atomicAdd).
//
// t_ij = cq_i + cq_j + TG*<C_i,C_j>;  d_ij = <m_i,m_j>;  term = exp2(t)*d^2.
// A-op K=16: [TGh(3),TGl(3),TGh(3),TGl(3),cqh,cql,1,1]
// B-op K=16: [Ch(3),Ch(3),Cl(3),Cl(3),1,1,cqh,cql]
// d:  A=[mh,ml,mh,ml,0^4], B=[mh,mh,ml,ml,0^4]   (exact hi/lo split)

#define NVERT 5023
#define NFACE 9976
#define BATCH 4
#define HALFP 9984             // per-mesh faces padded: 39 panels x 256
#define NTP   (2 * HALFP)      // 19968 faces per batch
#define NTOT  (BATCH * NTP)    // 79872
#define NCH   624              // j-chunks of 32 per batch
#define NPAN  78               // i-panels of 256
#define SPLITS 26

constexpr float GAMMA = 1.0f / (0.03f * 0.03f);
constexpr float LOG2E = 1.4426950408889634f;
constexpr float EPSV  = 1e-12f;

typedef _Float16 half8_t  __attribute__((ext_vector_type(8)));
typedef float    f32x16   __attribute__((ext_vector_type(16)));
typedef float    f32x2    __attribute__((ext_vector_type(2)));

__global__ __launch_bounds__(256)
void face_quant_kernel(const float* __restrict__ pred,
                       const float* __restrict__ targ,
                       const int*   __restrict__ faces,
                       _Float16*    __restrict__ fd,
                       float*       __restrict__ out) {
    int idx = blockIdx.x * 256 + threadIdx.x;
    if (idx == 0) out[0] = 0.0f;
    if (idx >= NTOT) return;

    int b     = idx / NTP;
    int s     = idx - b * NTP;
    int which = (s >= HALFP) ? 1 : 0;
    int f     = s - which * HALFP;

    _Float16* arec = fd + (size_t)idx * 32;
    _Float16* brec = fd + (size_t)NTOT * 32 + (size_t)idx * 32;

    if (f >= NFACE) {
        half8_t z = {};
        *(half8_t*)(arec + 0) = z; *(half8_t*)(arec + 8)  = z;
        *(half8_t*)(arec + 16) = z; *(half8_t*)(arec + 24) = z;
        *(half8_t*)(brec + 0) = z; *(half8_t*)(brec + 8)  = z;
        *(half8_t*)(brec + 16) = z; *(half8_t*)(brec + 24) = z;
        return;
    }

    const float* V = (which ? targ : pred) + (size_t)b * NVERT * 3;
    int i0 = faces[f * 3 + 0];
    int i1 = faces[f * 3 + 1];
    int i2 = faces[f * 3 + 2];

    float v0x = V[i0*3+0], v0y = V[i0*3+1], v0z = V[i0*3+2];
    float v1x = V[i1*3+0], v1y = V[i1*3+1], v1z = V[i1*3+2];
    float v2x = V[i2*3+0], v2y = V[i2*3+1], v2z = V[i2*3+2];

    const float third = 1.0f / 3.0f;
    float cx = (v0x + v1x + v2x) * third;
    float cy = (v0y + v1y + v2y) * third;
    float cz = (v0z + v1z + v2z) * third;

    float e1x = v1x - v0x, e1y = v1y - v0y, e1z = v1z - v0z;
    float e2x = v2x - v0x, e2y = v2y - v0y, e2z = v2z - v0z;

    float nx = 0.5f * (e1y * e2z - e1z * e2y);
    float ny = 0.5f * (e1z * e2x - e1x * e2z);
    float nz = 0.5f * (e1x * e2y - e1y * e2x);

    float L   = sqrtf(nx*nx + ny*ny + nz*nz);
    float inv = 1.0f / fmaxf(L, EPSV);
    float sc  = inv * sqrtf(L);            // m = Nn*sqrt(L)
    float mx = nx * sc, my = ny * sc, mz = nz * sc;

    const float TG = 2.0f * GAMMA * LOG2E;
    float tgx = TG * cx, tgy = TG * cy, tgz = TG * cz;
    float cq  = -GAMMA * LOG2E * (cx*cx + cy*cy + cz*cz);

    _Float16 TGxh = (_Float16)tgx; _Float16 TGxl = (_Float16)(tgx - (float)TGxh);
    _Float16 TGyh = (_Float16)tgy; _Float16 TGyl = (_Float16)(tgy - (float)TGyh);
    _Float16 TGzh = (_Float16)tgz; _Float16 TGzl = (_Float16)(tgz - (float)TGzh);
    _Float16 Cxh  = (_Float16)cx;  _Float16 Cxl  = (_Float16)(cx  - (float)Cxh);
    _Float16 Cyh  = (_Float16)cy;  _Float16 Cyl  = (_Float16)(cy  - (float)Cyh);
    _Float16 Czh  = (_Float16)cz;  _Float16 Czl  = (_Float16)(cz  - (float)Czh);
    _Float16 cqh  = (_Float16)cq;  _Float16 cql  = (_Float16)(cq  - (float)cqh);
    _Float16 mxh  = (_Float16)mx;  _Float16 mxl  = (_Float16)(mx  - (float)mxh);
    _Float16 myh  = (_Float16)my;  _Float16 myl  = (_Float16)(my  - (float)myh);
    _Float16 mzh  = (_Float16)mz;  _Float16 mzl  = (_Float16)(mz  - (float)mzh);
    _Float16 one  = (_Float16)1.0f;
    _Float16 zz   = (_Float16)0.0f;

    half8_t ta0 = {TGxh, TGyh, TGzh, TGxl, TGyl, TGzl, TGxh, TGyh};
    half8_t ta1 = {TGzh, TGxl, TGyl, TGzl, cqh,  cql,  one,  one };
    half8_t da0 = {mxh,  myh,  mzh,  mxl,  myl,  mzl,  mxh,  myh };
    half8_t da1 = {mzh,  mxl,  myl,  mzl,  zz,   zz,   zz,   zz  };
    half8_t tb0 = {Cxh,  Cyh,  Czh,  Cxh,  Cyh,  Czh,  Cxl,  Cyl };
    half8_t tb1 = {Czl,  Cxl,  Cyl,  Czl,  one,  one,  cqh,  cql };
    half8_t db0 = {mxh,  myh,  mzh,  mxh,  myh,  mzh,  mxl,  myl };
    half8_t db1 = {mzl,  mxl,  myl,  mzl,  zz,   zz,   zz,   zz  };

    *(half8_t*)(arec + 0)  = ta0;  *(half8_t*)(arec + 8)  = ta1;
    *(half8_t*)(arec + 16) = da0;  *(half8_t*)(arec + 24) = da1;
    *(half8_t*)(brec + 0)  = tb0;  *(half8_t*)(brec + 8)  = tb1;
    *(half8_t*)(brec + 16) = db0;  *(half8_t*)(brec + 24) = db1;
}

__device__ __forceinline__ half8_t ld8(const _Float16* p) {
    return *(const half8_t*)p;
}

__global__ __launch_bounds__(256, 4)
void pair_sum_kernel(const _Float16* __restrict__ fd,
                     float*          __restrict__ out) {
    const int b       = blockIdx.z;
    const int pairIdx = blockIdx.x / SPLITS;     // 0..38
    const int s       = blockIdx.x % SPLITS;

    const _Float16* Arec = fd;
    const _Float16* Brec = fd + (size_t)NTOT * 32;

    const int lane = threadIdx.x & 63;
    const int w    = threadIdx.x >> 6;
    const int col  = lane & 31;
    const int koff = (lane >> 5) * 8;

    const size_t bface = (size_t)b * NTP;
    const size_t JSTEP = (size_t)SPLITS * 32 * 32;

    float acc = 0.0f;

    #pragma unroll 1
    for (int h = 0; h < 2; ++h) {
        const int   P  = h ? (NPAN - 1 - pairIdx) : pairIdx;
        const int   c0 = 8 * P;
        const float si = (P < NPAN / 2) ? 1.0f : -1.0f;
        const int   iters = (NCH - c0 - s + SPLITS - 1) / SPLITS;
        if (iters <= 0) continue;

        // two i-tiles per wave: rows P*256 + w*32 (+128)
        const _Float16* ap0 = Arec + (bface + (size_t)(P * 256 + w * 32 + col)) * 32 + koff;
        const _Float16* ap1 = ap0 + (size_t)128 * 32;
        half8_t aT0 = ld8(ap0);
        half8_t aD0 = ld8(ap0 + 16);
        half8_t aT1 = ld8(ap1);
        half8_t aD1 = ld8(ap1 + 16);

        const _Float16* Bbase = Brec + (bface + (size_t)((c0 + s) * 32 + col)) * 32 + koff;

        // per-wave circular stagger: wave w starts at chunk k0 and wraps,
        // decorrelating the 4 waves' MFMA-wait windows (wave-uniform k0).
        const int k0 = (w * iters) >> 2;

        f32x16 z = {};

        #pragma unroll 1
        for (int seg = 0; seg < 2; ++seg) {
            const int kb = seg ? 0  : k0;
            const int ke = seg ? k0 : iters;
            if (kb >= ke) continue;

            const _Float16* pB = Bbase + (size_t)kb * JSTEP;
            half8_t bT = ld8(pB);
            half8_t bD = ld8(pB + 16);

            #pragma unroll 1
            for (int k = kb; k < ke; ++k) {
                // depth-1 branchless prefetch of next chunk (clamped)
                const _Float16* pN = (k + 1 < ke) ? (pB + JSTEP) : pB;
                half8_t nT = ld8(pN);
                half8_t nD = ld8(pN + 16);
                pB = pN;

                // one B-chunk feeds both i-tiles: 4 MFMAs / 2048 pairs
                f32x16 T0 = __builtin_amdgcn_mfma_f32_32x32x16_f16(aT0, bT, z, 0, 0, 0);
                f32x16 D0 = __builtin_amdgcn_mfma_f32_32x32x16_f16(aD0, bD, z, 0, 0, 0);
                f32x16 T1 = __builtin_amdgcn_mfma_f32_32x32x16_f16(aT1, bT, z, 0, 0, 0);
                f32x16 D1 = __builtin_amdgcn_mfma_f32_32x32x16_f16(aD1, bD, z, 0, 0, 0);

                // two independent packed epilogues
                f32x2 ts0 = {0.f, 0.f}, ts1 = {0.f, 0.f};
                #pragma unroll
                for (int r = 0; r < 16; r += 2) {
                    f32x2 e0 = {__builtin_amdgcn_exp2f(T0[r]),
                                __builtin_amdgcn_exp2f(T0[r + 1])};
                    f32x2 d0 = {D0[r], D0[r + 1]};
                    d0 = d0 * d0;
                    ts0 = e0 * d0 + ts0;
                    f32x2 e1 = {__builtin_amdgcn_exp2f(T1[r]),
                                __builtin_amdgcn_exp2f(T1[r + 1])};
                    f32x2 d1 = {D1[r], D1[r + 1]};
                    d1 = d1 * d1;
                    ts1 = e1 * d1 + ts1;
                }

                const int   jc  = c0 + s + SPLITS * k;
                const float sj  = (jc < NCH / 2) ? si : -si;
                const float wgt = (k == 0 && s < 8) ? 1.0f : 2.0f;
                acc = fmaf(sj * wgt, ts0.x + ts0.y + ts1.x + ts1.y, acc);

                bT = nT; bD = nD;
            }
        }
    }

    acc *= (1.0f / BATCH);

    #pragma unroll
    for (int off = 32; off > 0; off >>= 1)
        acc += __shfl_down(acc, off, 64);

    __shared__ float wsum[4];
    if (lane == 0) wsum[w] = acc;
    __syncthreads();
    if (threadIdx.x == 0)
        atomicAdd(out, wsum[0] + wsum[1] + wsum[2] + wsum[3]);
}

extern "C" void kernel_launch(void* const* d_in, const int* in_sizes, int n_in,
                              void* d_out, int out_size, void* d_ws, size_t ws_size,
                              hipStream_t stream) {
    const float* pred  = (const float*)d_in[0];
    const float* targ  = (const float*)d_in[1];
    const int*   faces = (const int*)d_in[2];
    float*       out   = (float*)d_out;
    _Float16*    fd    = (_Float16*)d_ws;   // 2 arrays x 79872 faces x 64 B = 10.2 MB

    face_quant_kernel<<<(NTOT + 255) / 256, 256, 0, stream>>>(
        pred, targ, faces, fd, out);

    dim3 grid((NPAN / 2) * SPLITS, 1, BATCH);   // 1014 x 1 x 4 = 4056 blocks
    pair_sum_kernel<<<grid, 256, 0, stream>>>(fd, out);
}

// Round 6
// 158.410 us; speedup vs baseline: 1.1243x; 1.0142x over previous
//
#include <hip/hip_runtime.h>

// Varifold loss, round 18: round-12 base (2 i-tiles/wave, 256-row panels,
// SPLITS=26, 32x32x16 f16 MFMA) with three zero-pressure VALU trims:
//  1. cross-iteration packed accumulator chains aa[4]; sign handled by a
//     single rare negate at the mesh-boundary crossing ktrig (SALU check),
//     one fold per panel; k=0 diagonal weight via one-time s<8 correction.
//     Per-iteration fold cost -> 0 (was ~22 cy).
//  2. 2x-unrolled ping-pong B registers: no rotation movs (was 16 cy).
//  3. clamp-free depth-1 prefetch: B region padded by 864 records so the
//     last prefetch over-reads harmlessly (loaded, never consumed).
//
// t_ij = cq_i + cq_j + TG*<C_i,C_j>;  d_ij = <m_i,m_j>;  term = exp2(t)*d^2.
// A-op K=16: [TGh(3),TGl(3),TGh(3),TGl(3),cqh,cql,1,1]
// B-op K=16: [Ch(3),Ch(3),Cl(3),Cl(3),1,1,cqh,cql]
// d:  A=[mh,ml,mh,ml,0^4], B=[mh,mh,ml,ml,0^4]   (exact hi/lo split)

#define NVERT 5023
#define NFACE 9976
#define BATCH 4
#define HALFP 9984             // per-mesh faces padded: 39 panels x 256
#define NTP   (2 * HALFP)      // 19968 faces per batch
#define NTOT  (BATCH * NTP)    // 79872
#define NCH   624              // j-chunks of 32 per batch
#define NPAN  78               // i-panels of 256
#define SPLITS 26
#define BPAD  (27 * 32)        // prefetch over-read pad (records)

constexpr float GAMMA = 1.0f / (0.03f * 0.03f);
constexpr float LOG2E = 1.4426950408889634f;
constexpr float EPSV  = 1e-12f;

typedef _Float16 half8_t  __attribute__((ext_vector_type(8)));
typedef float    f32x16   __attribute__((ext_vector_type(16)));
typedef float    f32x2    __attribute__((ext_vector_type(2)));

__global__ __launch_bounds__(256)
void face_quant_kernel(const float* __restrict__ pred,
                       const float* __restrict__ targ,
                       const int*   __restrict__ faces,
                       _Float16*    __restrict__ fd,
                       float*       __restrict__ out) {
    int idx = blockIdx.x * 256 + threadIdx.x;
    if (idx == 0) out[0] = 0.0f;
    if (idx >= NTOT) return;

    int b     = idx / NTP;
    int s     = idx - b * NTP;
    int which = (s >= HALFP) ? 1 : 0;
    int f     = s - which * HALFP;

    _Float16* arec = fd + (size_t)idx * 32;
    _Float16* brec = fd + (size_t)NTOT * 32 + (size_t)idx * 32;

    if (f >= NFACE) {
        half8_t z = {};
        *(half8_t*)(arec + 0) = z; *(half8_t*)(arec + 8)  = z;
        *(half8_t*)(arec + 16) = z; *(half8_t*)(arec + 24) = z;
        *(half8_t*)(brec + 0) = z; *(half8_t*)(brec + 8)  = z;
        *(half8_t*)(brec + 16) = z; *(half8_t*)(brec + 24) = z;
        return;
    }

    const float* V = (which ? targ : pred) + (size_t)b * NVERT * 3;
    int i0 = faces[f * 3 + 0];
    int i1 = faces[f * 3 + 1];
    int i2 = faces[f * 3 + 2];

    float v0x = V[i0*3+0], v0y = V[i0*3+1], v0z = V[i0*3+2];
    float v1x = V[i1*3+0], v1y = V[i1*3+1], v1z = V[i1*3+2];
    float v2x = V[i2*3+0], v2y = V[i2*3+1], v2z = V[i2*3+2];

    const float third = 1.0f / 3.0f;
    float cx = (v0x + v1x + v2x) * third;
    float cy = (v0y + v1y + v2y) * third;
    float cz = (v0z + v1z + v2z) * third;

    float e1x = v1x - v0x, e1y = v1y - v0y, e1z = v1z - v0z;
    float e2x = v2x - v0x, e2y = v2y - v0y, e2z = v2z - v0z;

    float nx = 0.5f * (e1y * e2z - e1z * e2y);
    float ny = 0.5f * (e1z * e2x - e1x * e2z);
    float nz = 0.5f * (e1x * e2y - e1y * e2x);

    float L   = sqrtf(nx*nx + ny*ny + nz*nz);
    float inv = 1.0f / fmaxf(L, EPSV);
    float sc  = inv * sqrtf(L);            // m = Nn*sqrt(L)
    float mx = nx * sc, my = ny * sc, mz = nz * sc;

    const float TG = 2.0f * GAMMA * LOG2E;
    float tgx = TG * cx, tgy = TG * cy, tgz = TG * cz;
    float cq  = -GAMMA * LOG2E * (cx*cx + cy*cy + cz*cz);

    _Float16 TGxh = (_Float16)tgx; _Float16 TGxl = (_Float16)(tgx - (float)TGxh);
    _Float16 TGyh = (_Float16)tgy; _Float16 TGyl = (_Float16)(tgy - (float)TGyh);
    _Float16 TGzh = (_Float16)tgz; _Float16 TGzl = (_Float16)(tgz - (float)TGzh);
    _Float16 Cxh  = (_Float16)cx;  _Float16 Cxl  = (_Float16)(cx  - (float)Cxh);
    _Float16 Cyh  = (_Float16)cy;  _Float16 Cyl  = (_Float16)(cy  - (float)Cyh);
    _Float16 Czh  = (_Float16)cz;  _Float16 Czl  = (_Float16)(cz  - (float)Czh);
    _Float16 cqh  = (_Float16)cq;  _Float16 cql  = (_Float16)(cq  - (float)cqh);
    _Float16 mxh  = (_Float16)mx;  _Float16 mxl  = (_Float16)(mx  - (float)mxh);
    _Float16 myh  = (_Float16)my;  _Float16 myl  = (_Float16)(my  - (float)myh);
    _Float16 mzh  = (_Float16)mz;  _Float16 mzl  = (_Float16)(mz  - (float)mzh);
    _Float16 one  = (_Float16)1.0f;
    _Float16 zz   = (_Float16)0.0f;

    half8_t ta0 = {TGxh, TGyh, TGzh, TGxl, TGyl, TGzl, TGxh, TGyh};
    half8_t ta1 = {TGzh, TGxl, TGyl, TGzl, cqh,  cql,  one,  one };
    half8_t da0 = {mxh,  myh,  mzh,  mxl,  myl,  mzl,  mxh,  myh };
    half8_t da1 = {mzh,  mxl,  myl,  mzl,  zz,   zz,   zz,   zz  };
    half8_t tb0 = {Cxh,  Cyh,  Czh,  Cxh,  Cyh,  Czh,  Cxl,  Cyl };
    half8_t tb1 = {Czl,  Cxl,  Cyl,  Czl,  one,  one,  cqh,  cql };
    half8_t db0 = {mxh,  myh,  mzh,  mxh,  myh,  mzh,  mxl,  myl };
    half8_t db1 = {mzl,  mxl,  myl,  mzl,  zz,   zz,   zz,   zz  };

    *(half8_t*)(arec + 0)  = ta0;  *(half8_t*)(arec + 8)  = ta1;
    *(half8_t*)(arec + 16) = da0;  *(half8_t*)(arec + 24) = da1;
    *(half8_t*)(brec + 0)  = tb0;  *(half8_t*)(brec + 8)  = tb1;
    *(half8_t*)(brec + 16) = db0;  *(half8_t*)(brec + 24) = db1;
}

__device__ __forceinline__ half8_t ld8(const _Float16* p) {
    return *(const half8_t*)p;
}

// One j-chunk body: 4 MFMAs, unconditional prefetch into (NT_,ND_),
// rare sign-negate at ktrig, epilogue into 4 packed chains.
// T0 uses chains (r>>1)&3, T1 uses ((r>>1)+2)&3 -> dep distance 4 fmas.
#define KBODY(CT_, CD_, NT_, ND_, K_)                                        \
    {                                                                        \
        f32x16 T0 = __builtin_amdgcn_mfma_f32_32x32x16_f16(aT0, CT_, z, 0, 0, 0); \
        f32x16 D0 = __builtin_amdgcn_mfma_f32_32x32x16_f16(aD0, CD_, z, 0, 0, 0); \
        f32x16 T1 = __builtin_amdgcn_mfma_f32_32x32x16_f16(aT1, CT_, z, 0, 0, 0); \
        f32x16 D1 = __builtin_amdgcn_mfma_f32_32x32x16_f16(aD1, CD_, z, 0, 0, 0); \
        pB += JSTEP;                                                         \
        NT_ = ld8(pB);                                                       \
        ND_ = ld8(pB + 16);                                                  \
        if ((K_) == ktrig) {                                                 \
            aa[0] = -aa[0]; aa[1] = -aa[1]; aa[2] = -aa[2]; aa[3] = -aa[3];  \
        }                                                                    \
        _Pragma("unroll")                                                    \
        for (int r = 0; r < 16; r += 2) {                                    \
            f32x2 e0 = {__builtin_amdgcn_exp2f(T0[r]),                       \
                        __builtin_amdgcn_exp2f(T0[r + 1])};                  \
            f32x2 d0 = {D0[r], D0[r + 1]};                                   \
            d0 = d0 * d0;                                                    \
            aa[(r >> 1) & 3] = e0 * d0 + aa[(r >> 1) & 3];                   \
            f32x2 e1 = {__builtin_amdgcn_exp2f(T1[r]),                       \
                        __builtin_amdgcn_exp2f(T1[r + 1])};                  \
            f32x2 d1 = {D1[r], D1[r + 1]};                                   \
            d1 = d1 * d1;                                                    \
            aa[((r >> 1) + 2) & 3] = e1 * d1 + aa[((r >> 1) + 2) & 3];       \
        }                                                                    \
    }

__global__ __launch_bounds__(256, 4)
void pair_sum_kernel(const _Float16* __restrict__ fd,
                     float*          __restrict__ out) {
    const int b       = blockIdx.z;
    const int pairIdx = blockIdx.x / SPLITS;     // 0..38
    const int s       = blockIdx.x % SPLITS;

    const _Float16* Arec = fd;
    const _Float16* Brec = fd + (size_t)NTOT * 32;

    const int lane = threadIdx.x & 63;
    const int w    = threadIdx.x >> 6;
    const int col  = lane & 31;
    const int koff = (lane >> 5) * 8;

    const size_t bface = (size_t)b * NTP;
    const size_t JSTEP = (size_t)SPLITS * 32 * 32;

    float acc = 0.0f;
    const f32x16 z = {};

    #pragma unroll 1
    for (int h = 0; h < 2; ++h) {
        const int   P  = h ? (NPAN - 1 - pairIdx) : pairIdx;
        const int   c0 = 8 * P;
        const float si = (P < NPAN / 2) ? 1.0f : -1.0f;
        const int   iters = (NCH - c0 - s + SPLITS - 1) / SPLITS;
        if (iters <= 0) continue;

        // sign regions: chunks k < kcross have sign si, k >= kcross have -si
        const int   rem      = NCH / 2 - (c0 + s);
        const int   kcross   = (rem > 0) ? ((rem + SPLITS - 1) / SPLITS) : 0;
        const float sign0    = (kcross > 0) ? si : -si;
        const float signLast = (kcross >= iters) ? si : -si;
        const int   ktrig    = (kcross >= 1 && kcross < iters) ? kcross : -1;

        // two i-tiles per wave: rows P*256 + w*32 (+128)
        const _Float16* ap0 = Arec + (bface + (size_t)(P * 256 + w * 32 + col)) * 32 + koff;
        const _Float16* ap1 = ap0 + (size_t)128 * 32;
        half8_t aT0 = ld8(ap0);
        half8_t aD0 = ld8(ap0 + 16);
        half8_t aT1 = ld8(ap1);
        half8_t aD1 = ld8(ap1 + 16);

        const _Float16* pB =
            Brec + (bface + (size_t)((c0 + s) * 32 + col)) * 32 + koff;
        half8_t bT = ld8(pB);
        half8_t bD = ld8(pB + 16);
        half8_t nT, nD;

        f32x2 aa[4] = {};

        // ---- k = 0 (prefetches chunk 1 into nT/nD; pad covers over-read) ----
        KBODY(bT, bD, nT, nD, 0)

        // diagonal chunk has weight 1 (not 2) when s < 8: subtract one copy.
        // chains currently hold exactly t0; final accounting gives it 2*sign0.
        if (s < 8) {
            f32x2 A2 = (aa[0] + aa[1]) + (aa[2] + aa[3]);
            acc = fmaf(-sign0, A2.x + A2.y, acc);
        }

        // ---- main loop: 2x-unrolled ping-pong, no movs, no per-iter fold ----
        int k = 1;
        if (k < iters) {
            for (;;) {
                KBODY(nT, nD, bT, bD, k)
                if (++k >= iters) break;
                KBODY(bT, bD, nT, nD, k)
                if (++k >= iters) break;
            }
        }

        f32x2 A2 = (aa[0] + aa[1]) + (aa[2] + aa[3]);
        acc = fmaf(2.0f * signLast, A2.x + A2.y, acc);
    }

    acc *= (1.0f / BATCH);

    #pragma unroll
    for (int off = 32; off > 0; off >>= 1)
        acc += __shfl_down(acc, off, 64);

    __shared__ float wsum[4];
    if (lane == 0) wsum[w] = acc;
    __syncthreads();
    if (threadIdx.x == 0)
        atomicAdd(out, wsum[0] + wsum[1] + wsum[2] + wsum[3]);
}

extern "C" void kernel_launch(void* const* d_in, const int* in_sizes, int n_in,
                              void* d_out, int out_size, void* d_ws, size_t ws_size,
                              hipStream_t stream) {
    const float* pred  = (const float*)d_in[0];
    const float* targ  = (const float*)d_in[1];
    const int*   faces = (const int*)d_in[2];
    float*       out   = (float*)d_out;
    _Float16*    fd    = (_Float16*)d_ws;
    // layout: A region NTOT*32 halfs | B region NTOT*32 halfs | BPAD*32 pad
    // = 10.22 MB + 54 KB (pad read-only, values discarded)

    face_quant_kernel<<<(NTOT + 255) / 256, 256, 0, stream>>>(
        pred, targ, faces, fd, out);

    dim3 grid((NPAN / 2) * SPLITS, 1, BATCH);   // 1014 x 1 x 4 = 4056 blocks
    pair_sum_kernel<<<grid, 256, 0, stream>>>(fd, out);
}